// Round 8
// baseline (615.841 us; speedup 1.0000x reference)
//
#include <hip/hip_runtime.h>
#include <cstdio>

// CapsuleLayer dynamic routing, MI355X (gfx950). Round 8.
// Round-7 post-mortem: k_passN FETCH 128 MB / WRITE 202 MB vs analytic
// 38 r / 16.7 w. Cause: part fp16 [bg][jd][ic][col] -> 64-B chunks, every
// 128-B line shared by blocks ic/ic+1 on different XCDs + 2-B lane stores =
// partial-sector RMW storm. Also Wp/xp read twice (bg0/bg1 block pairs).
// Fixes:
//  (1) part -> fp32, writer-contiguous [bg][ic][jd][col]: full 128-B lines,
//      dword stores, zero cross-block sharing.  (predict WRITE 202->35 MB)
//  (2) k_passN merges both bg in one 1024-thr block (16 waves, 2 mt/wave,
//      light ~115-reg body): one Wp/xp read.     (predict FETCH 128->45 MB)
// Structure: k_pass0 (stage W+x->LDS frags, pass0, export Wp/xp) ; k_rs<0> ;
// k_passN ; k_rs<1> ; k_passN ; k_rs<2>.

#define NC     32
#define JDIM   512
#define NICB   256          // i-chunk count
#define IPB    8
#define EPS_SQ 1e-7f

typedef short    s16x4  __attribute__((ext_vector_type(4)));
typedef short    s16x8  __attribute__((ext_vector_type(8)));
typedef float    f32x16 __attribute__((ext_vector_type(16)));
typedef unsigned u32;

__device__ inline short bfc(float f) {
  u32 u = __builtin_bit_cast(u32, f);
  u32 r = (u + 0x7FFFu + ((u >> 16) & 1u)) >> 16;
  return (short)(unsigned short)r;
}
__device__ inline u32 pk2(float a, float b) {
  return (u32)(unsigned short)bfc(a) | ((u32)(unsigned short)bfc(b) << 16);
}
__device__ inline float bf2f(short s) {
  return __builtin_bit_cast(float, ((u32)(unsigned short)s) << 16);
}

// ---------------------------------------------------------------------------
// Pass 0 + fragment export. 256 blocks (ic) x 512 thr (8 waves).
// LDS: wfrag [8 i][16 mt][64 l][4 u32] = 128K ; xfrag [8 i][2 bg][64 l][4] = 16K.
// Waves 0-3: bg 0, waves 4-7: bg 1; wave owns mt = wm*4 + m (m<4).
// ---------------------------------------------------------------------------
__global__ __launch_bounds__(512) void k_pass0(const float* __restrict__ W,
                                               const float* __restrict__ x,
                                               unsigned short* __restrict__ Wp,
                                               unsigned short* __restrict__ xp,
                                               float* __restrict__ part) {
  extern __shared__ u32 lds[];
  u32* wfrag = lds;             // 32768 u32
  u32* xfrag = lds + 32768;     // 4096 u32
  const int ic  = blockIdx.x;
  const int tid = threadIdx.x;
  const int w   = tid >> 6;
  const int l   = tid & 63;
  const int col = l & 31;
  const int hi  = l >> 5;
  const int bg  = w >> 2;
  const int wm  = w & 3;
  const int i0  = ic * IPB;

  // ---- stage x into LDS fragments ----
  {
    const int xb = tid >> 3, xi = tid & 7;
    const float* xsrc = x + ((size_t)xb * 2048 + i0 + xi) * 16;
    float4 xv0 = *(const float4*)(xsrc);
    float4 xv1 = *(const float4*)(xsrc + 4);
    float4 xv2 = *(const float4*)(xsrc + 8);
    float4 xv3 = *(const float4*)(xsrc + 12);
    int lbg = xb >> 5, lc = xb & 31;
    u32* d0 = xfrag + (((size_t)xi * 2 + lbg) * 64 + lc) * 4;       // hi=0
    d0[0] = pk2(xv0.x, xv0.y); d0[1] = pk2(xv0.z, xv0.w);
    d0[2] = pk2(xv2.x, xv2.y); d0[3] = pk2(xv2.z, xv2.w);
    u32* d1 = d0 + 32 * 4;                                          // hi=1
    d1[0] = pk2(xv1.x, xv1.y); d1[1] = pk2(xv1.z, xv1.w);
    d1[2] = pk2(xv3.x, xv3.y); d1[3] = pk2(xv3.z, xv3.w);
  }
  // ---- stage W into LDS fragments (coalesced reads, 4-float4 chunks) ----
  {
    const float* wsrc = W + (size_t)i0 * 8192;
#pragma unroll
    for (int ii = 0; ii < IPB; ii++) {
      float4 v0 = *(const float4*)(wsrc + (size_t)ii * 8192 + (size_t)(0 * 512 + tid) * 4);
      float4 v1 = *(const float4*)(wsrc + (size_t)ii * 8192 + (size_t)(1 * 512 + tid) * 4);
      float4 v2 = *(const float4*)(wsrc + (size_t)ii * 8192 + (size_t)(2 * 512 + tid) * 4);
      float4 v3 = *(const float4*)(wsrc + (size_t)ii * 8192 + (size_t)(3 * 512 + tid) * 4);
#pragma unroll
      for (int q4 = 0; q4 < 4; q4++) {
        float4 v = (q4 == 0) ? v0 : (q4 == 1) ? v1 : (q4 == 2) ? v2 : v3;
        int idx = q4 * 512 + tid;          // float4 index within W[i]
        int jd = idx >> 2, q = idx & 3;    // q = k/4
        u32* d = wfrag + (((size_t)ii * 16 + (jd >> 5)) * 64 +
                          (q & 1) * 32 + (jd & 31)) * 4 + (q >> 1) * 2;
        d[0] = pk2(v.x, v.y);
        d[1] = pk2(v.z, v.w);
      }
    }
  }
  __syncthreads();

  // ---- export fragments to global (coalesced LDS read + global store) ----
  {
    const size_t gfb = (size_t)ic * 8192;          // global frag base
#pragma unroll
    for (int q = 0; q < 16; q++) {
      int fid = q * 512 + tid;                     // 0..8191
      uint4 v = *(const uint4*)(wfrag + (size_t)fid * 4);
      *(uint4*)(Wp + (gfb + fid) * 8) = v;
    }
    u32* xp32 = (u32*)xp;
#pragma unroll
    for (int q = 0; q < 2; q++) {
      int idx4 = q * 512 + tid;                    // uint4 index 0..1023
      uint4 v = *(const uint4*)(xfrag + (size_t)idx4 * 4);
      *(uint4*)(xp32 + (size_t)ic * 4096 + (size_t)idx4 * 4) = v;
    }
  }

  // ---- pass-0 compute (uniform c = 1/32): pure MFMA accumulate ----
  f32x16 sa[4];
#pragma unroll
  for (int m = 0; m < 4; m++)
#pragma unroll
    for (int q = 0; q < 16; q++) sa[m][q] = 0.f;

  for (int ii = 0; ii < IPB; ii++) {
    s16x8 xv = *(const s16x8*)(xfrag + (((size_t)ii * 2 + bg) * 64 + l) * 4);
    s16x4 xlo = __builtin_shufflevector(xv, xv, 0, 1, 2, 3);
    s16x4 xhi = __builtin_shufflevector(xv, xv, 4, 5, 6, 7);
#pragma unroll
    for (int m = 0; m < 4; m++) {
      int mt = wm * 4 + m;
      s16x8 wv = *(const s16x8*)(wfrag + (((size_t)ii * 16 + mt) * 64 + l) * 4);
      s16x4 wlo = __builtin_shufflevector(wv, wv, 0, 1, 2, 3);
      s16x4 whi = __builtin_shufflevector(wv, wv, 4, 5, 6, 7);
      sa[m] = __builtin_amdgcn_mfma_f32_32x32x8bf16_1k(wlo, xlo, sa[m], 0, 0, 0);
      sa[m] = __builtin_amdgcn_mfma_f32_32x32x8bf16_1k(whi, xhi, sa[m], 0, 0, 0);
    }
  }

  // part[bg][ic][jd][col] fp32: full-line dword stores, block-contiguous
#pragma unroll
  for (int m = 0; m < 4; m++) {
    int mt = wm * 4 + m;
#pragma unroll
    for (int r = 0; r < 16; r++) {
      int row = (r & 3) + 8 * (r >> 2) + 4 * hi;
      int jd = mt * 32 + row;
      part[(((size_t)bg * NICB + ic) * JDIM + jd) * 32 + col] =
          sa[m][r] * (1.0f / 32.0f);
    }
  }
}

// ---------------------------------------------------------------------------
// Routing pass (p>=1). 256 blocks (ic) x 1024 thr (16 waves).
// Waves 0-7: bg 0, waves 8-15: bg 1; wave owns mt = wm*2, wm*2+1 (wm = w&7).
// Streams Wp/xp global->reg->MFMA (ONE read of each; both bg share).
// ---------------------------------------------------------------------------
__global__ __launch_bounds__(1024) void k_passN(const unsigned short* __restrict__ Wp,
                                                const unsigned short* __restrict__ xp,
                                                const float* __restrict__ ST,
                                                float* __restrict__ part) {
  __shared__ float zbuf[2][16][33];
  const int ic  = blockIdx.x;
  const int tid = threadIdx.x;
  const int w   = tid >> 6;
  const int l   = tid & 63;
  const int col = l & 31;
  const int hi  = l >> 5;
  const int bg  = w >> 3;
  const int wm  = w & 7;

  f32x16 sa[2];
#pragma unroll
  for (int m = 0; m < 2; m++)
#pragma unroll
    for (int q = 0; q < 16; q++) sa[m][q] = 0.f;

  // S packed bf16 (svA: acc rows 0..7 -> j even; svB: rows 8..15 -> j odd)
  s16x8 svA[2], svB[2];
#pragma unroll
  for (int m = 0; m < 2; m++) {
    int mt = wm * 2 + m;
#pragma unroll
    for (int r = 0; r < 16; r++) {
      int row = (r & 3) + 8 * (r >> 2) + 4 * hi;
      short h = bfc(ST[(size_t)(mt * 32 + row) * 64 + bg * 32 + col]);
      if (r < 8) svA[m][r] = h; else svB[m][r - 8] = h;
    }
  }

  for (int ii = 0; ii < IPB; ii++) {
    int i = ic * IPB + ii;
    s16x8 xv = *(const s16x8*)(xp + ((size_t)i * 2 + bg) * 512 + (size_t)l * 8);
    s16x4 xlo = __builtin_shufflevector(xv, xv, 0, 1, 2, 3);
    s16x4 xhi = __builtin_shufflevector(xv, xv, 4, 5, 6, 7);

    f32x16 D[2];
#pragma unroll
    for (int m = 0; m < 2; m++) {
      int mt = wm * 2 + m;
      s16x8 wv = *(const s16x8*)(Wp + (((size_t)i * 16 + mt) * 64 + l) * 8);
      s16x4 wlo = __builtin_shufflevector(wv, wv, 0, 1, 2, 3);
      s16x4 whi = __builtin_shufflevector(wv, wv, 4, 5, 6, 7);
      f32x16 acc;
#pragma unroll
      for (int q = 0; q < 16; q++) acc[q] = 0.f;
      acc = __builtin_amdgcn_mfma_f32_32x32x8bf16_1k(wlo, xlo, acc, 0, 0, 0);
      D[m] = __builtin_amdgcn_mfma_f32_32x32x8bf16_1k(whi, xhi, acc, 0, 0, 0);
    }

    // logits -> exp in-register; only partial Z crosses waves
    float ee[2], eo[2], zl = 0.f;
#pragma unroll
    for (int m = 0; m < 2; m++) {
      float pe = 0.f, po = 0.f;
#pragma unroll
      for (int r = 0; r < 8; r++) pe += D[m][r]     * bf2f(svA[m][r]);
#pragma unroll
      for (int r = 0; r < 8; r++) po += D[m][r + 8] * bf2f(svB[m][r]);
      pe += __shfl_xor(pe, 32);     // other d-half lives in lane^32
      po += __shfl_xor(po, 32);
      ee[m] = __expf(pe);
      eo[m] = __expf(po);
      zl += ee[m] + eo[m];
    }
    if (l < 32) zbuf[ii & 1][w][col] = zl;
    __syncthreads();
    float Z = 0.f;
#pragma unroll
    for (int ww = 0; ww < 8; ww++) Z += zbuf[ii & 1][bg * 8 + ww][col];
    float rz = 1.0f / Z;
#pragma unroll
    for (int m = 0; m < 2; m++) {
      float ce = ee[m] * rz, co = eo[m] * rz;
#pragma unroll
      for (int r = 0; r < 8; r++) sa[m][r]     += ce * D[m][r];
#pragma unroll
      for (int r = 0; r < 8; r++) sa[m][r + 8] += co * D[m][r + 8];
    }
  }

  // part[bg][ic][jd][col] fp32: full-line dword stores, block-contiguous
#pragma unroll
  for (int m = 0; m < 2; m++) {
    int mt = wm * 2 + m;
#pragma unroll
    for (int r = 0; r < 16; r++) {
      int row = (r & 3) + 8 * (r >> 2) + 4 * hi;
      int jd = mt * 32 + row;
      part[(((size_t)bg * NICB + ic) * JDIM + jd) * 32 + col] = sa[m][r];
    }
  }
}

// ---------------------------------------------------------------------------
// Fused reduce (over 256 ic) + squash + ST/out update. 64 blocks x 512 thr.
// part[bg][ic][jd][col] fp32. P=0: ST = o ; P=1: ST += o ; P=2: out = o.
// ---------------------------------------------------------------------------
template <int P>
__global__ __launch_bounds__(512) void k_rs(const float* __restrict__ part,
                                            float* __restrict__ ST,
                                            float* __restrict__ out) {
  __shared__ float sl[16][33];
  int bid = blockIdx.x;
  int rbg = bid & 1, j = bid >> 1;
  int t = threadIdx.x;
  int b = t & 31, d = t >> 5;
  int jd = j * 16 + d;
  const float* pb = part + ((size_t)rbg * NICB * JDIM + jd) * 32 + b;
  float a[8];
#pragma unroll
  for (int k = 0; k < 8; k++) a[k] = 0.f;
  for (int q = 0; q < NICB; q += 8) {
#pragma unroll
    for (int k = 0; k < 8; k++)
      a[k] += pb[(size_t)(q + k) * JDIM * 32];
  }
  float s = ((a[0] + a[1]) + (a[2] + a[3])) + ((a[4] + a[5]) + (a[6] + a[7]));
  sl[d][b] = s * s;
  __syncthreads();
  float s2 = 0.f;
#pragma unroll
  for (int dd = 0; dd < 16; dd++) s2 += sl[dd][b];
  float o = s * s2 / ((1.0f + s2) * sqrtf(s2 + EPS_SQ));
  if (P == 2) {
    out[((size_t)(rbg * 32 + b) * NC + j) * 16 + d] = o;
  } else if (P == 0) {
    ST[(size_t)jd * 64 + rbg * 32 + b] = o;
  } else {
    ST[(size_t)jd * 64 + rbg * 32 + b] += o;
  }
}

// ---------------------------------------------------------------------------
extern "C" void kernel_launch(void* const* d_in, const int* in_sizes, int n_in,
                              void* d_out, int out_size, void* d_ws, size_t ws_size,
                              hipStream_t stream) {
  (void)in_sizes; (void)n_in; (void)out_size;
  const float* x = (const float*)d_in[0];
  const float* W = (const float*)d_in[1];
  float* out = (float*)d_out;

  const size_t off_st = 0;                                         // 128K (pad 256K)
  const size_t off_pt = (size_t)256 << 10;
  const size_t pt_sz  = (size_t)2 * NICB * JDIM * 32 * 4;          // 33.55 MB
  const size_t off_xp = off_pt + pt_sz;
  const size_t xp_sz  = (size_t)2048 * 2 * 512 * 2;                // 4.19 MB
  const size_t off_wp = off_xp + xp_sz;
  const size_t wp_sz  = (size_t)2048 * 1024 * 16;                  // 33.55 MB
  const size_t need   = off_wp + wp_sz + 1024;
  if (ws_size < need) { fprintf(stderr, "[caps] ws too small %zu < %zu\n", ws_size, need); return; }

  float*          ST   = (float*)((char*)d_ws + off_st);
  float*          part = (float*)((char*)d_ws + off_pt);
  unsigned short* xp   = (unsigned short*)((char*)d_ws + off_xp);
  unsigned short* Wp   = (unsigned short*)((char*)d_ws + off_wp);

  const int lds0 = 36864 * 4;   // 147456 B
  hipFuncSetAttribute(reinterpret_cast<const void*>(k_pass0),
                      hipFuncAttributeMaxDynamicSharedMemorySize, lds0);

  k_pass0<<<dim3(256), dim3(512), lds0, stream>>>(W, x, Wp, xp, part);
  k_rs<0><<<dim3(64), dim3(512), 0, stream>>>(part, ST, out);
  k_passN<<<dim3(256), dim3(1024), 0, stream>>>(Wp, xp, ST, part);
  k_rs<1><<<dim3(64), dim3(512), 0, stream>>>(part, ST, out);
  k_passN<<<dim3(256), dim3(1024), 0, stream>>>(Wp, xp, ST, part);
  k_rs<2><<<dim3(64), dim3(512), 0, stream>>>(part, ST, out);
}